// Round 7
// baseline (511.372 us; speedup 1.0000x reference)
//
#include <hip/hip_runtime.h>
#include <hip/hip_bf16.h>
#include <hip/hip_cooperative_groups.h>

namespace cg = cooperative_groups;

// ---------------- problem constants ----------------
constexpr int B = 64;
constexpr int NG = 16;
constexpr int NSH = 112;
constexpr int N = 128;          // nodes per graph
constexpr int NN = B * N;       // 8192 total nodes
constexpr int L = 5;

// ---------------- workspace layout (float offsets), double-buffered ----------------
constexpr int OFF_H     = 0;                    // [8192][32] f32 (owner-block access only)
constexpr int OFF_P0    = OFF_H + NN * 32;      // [8192][2]  f32
constexpr int OFF_P1    = OFF_P0 + NN * 2;
constexpr int OFF_TEMB0 = OFF_P1 + NN * 2;      // [64][32]
constexpr int OFF_TEMB1 = OFF_TEMB0 + B * 32;
constexpr int OFF_HA0   = OFF_TEMB1 + B * 32;   // [8192][32] f32
constexpr int OFF_HA1   = OFF_HA0 + NN * 32;
constexpr int OFF_HB0   = OFF_HA1 + NN * 32;    // [8192][32] ushort bf16 (NN*16 floats)
constexpr int OFF_HB1   = OFF_HB0 + NN * 16;

typedef __attribute__((ext_vector_type(8))) short bf16x8;
typedef __attribute__((ext_vector_type(4))) float f32x4;

// ---------------- math helpers ----------------
__device__ __forceinline__ float fsigmoid(float x) {
    return __builtin_amdgcn_rcpf(1.0f + __expf(-x));
}
__device__ __forceinline__ float fsilu(float x) { return x * fsigmoid(x); }
__device__ __forceinline__ short f2bfs(float f) {           // RNE
    union { __hip_bfloat16 b; short s; } u; u.b = __float2bfloat16(f); return u.s;
}
__device__ __forceinline__ float bf2f(unsigned short u) {
    union { unsigned int i; float f; } v; v.i = ((unsigned int)u) << 16; return v.f;
}
// single-inst truncation pack: dst = bf16(hi)<<16 | bf16(lo)
__device__ __forceinline__ unsigned int pk_trunc(float lo, float hi) {
    union { float f; unsigned int u; } a, b;
    a.f = hi; b.f = lo;
    return __builtin_amdgcn_perm(a.u, b.u, 0x07060302u);
}

// ---------------- setup + pre(layer 0): h, p, temb0, HA0, HB0 ----------------
// 1024 blocks x 256 thr; block = 8 nodes of one graph.
__global__ __launch_bounds__(256) void setup_pre_kernel(
    float* __restrict__ ws,
    const float* __restrict__ pos, const int* __restrict__ tsteps,
    const float* __restrict__ goal_pos,
    const float* __restrict__ W_hin, const float* __restrict__ b_hin,
    const float* __restrict__ W_msg1, const float* __restrict__ b_msg1)
{
    __shared__ float sT[32];
    const int t = threadIdx.x, bx = blockIdx.x;
    const int tid = bx * 256 + t;              // 0..262143 == NN*32
    const int c = tid & 31, node = tid >> 5, g = node >> 7, local = node & 127;
    const int row = (local < NG) ? 0 : 1;

    if (t < 32) {                              // temb for this block's graph
        const float tf = (float)tsteps[g];
        const int jj = (t < 16) ? t : (t - 16);
        const float ang = tf * expf(-logf(10000.0f) * (float)jj / 16.0f);
        sT[t] = (t < 16) ? cosf(ang) : sinf(ang);
    }
    __syncthreads();
    if ((bx & 15) == 0 && t < 32) ws[OFF_TEMB0 + g * 32 + t] = sT[t];

    ws[OFF_H + tid] = W_hin[row * 32 + c] + b_hin[c];     // h init

    if (tid < NN * 2) {                        // p init -> P0
        const int d = tid & 1, nd = tid >> 1, g0 = nd >> 7, loc = nd & 127;
        ws[OFF_P0 + tid] = (loc < NG) ? goal_pos[loc * 2 + d]
                                      : pos[(g0 * NSH + (loc - NG)) * 2 + d];
    }

    // pre layer 0 (h is type-determined: W_hin row + b_hin)
    const float* __restrict__ W1 = W_msg1;
    float accA = b_msg1[c], accB = 0.f;
#pragma unroll
    for (int k = 0; k < 32; ++k) {
        const float hk = W_hin[row * 32 + k] + b_hin[k];
        accA += hk * W1[k * 32 + c];
        accB += hk * W1[(32 + k) * 32 + c];
    }
#pragma unroll
    for (int k = 0; k < 32; ++k)
        accA += sT[k] * W1[(65 + k) * 32 + c];
    ws[OFF_HA0 + tid] = accA;
    ((unsigned short*)(ws + OFF_HB0))[tid] = (unsigned short)f2bfs(accB);
}

// ---------------- fused 5-layer cooperative kernel (templated) ----------------
// NQP = blocks per graph: 8 -> 512 blocks x 16 dsts; 4 -> 256 blocks x 32 dsts.
// R6 lesson: hipLaunchCooperativeKernel REJECTS grids exceeding true residency
// (occupancy has been pinned ~1.2 blocks/CU all session) — output stayed zero.
// Launcher now queries hipOccupancyMaxActiveBlocksPerMultiprocessor and picks
// the largest valid variant; falls back to per-layer dispatches otherwise.
// Body = R5's verified 32-dst structure (passed) parameterized; R4's 2-dst ILP.
// Race safety: edge reads parity l&1 HA/HB/P; epilogue writes parity (l+1)&1,
// own-block H/P rows, single-writer TEMB (qp==0); grid.sync() between layers.
template <int NQP>
__global__ __attribute__((amdgpu_flat_work_group_size(256, 256)))
__attribute__((amdgpu_waves_per_eu(2, 4))) void fused_layers_kernel(
    float* __restrict__ ws,
    const float* __restrict__ W_msg1, const float* __restrict__ b_msg1,
    const float* __restrict__ W_msg2, const float* __restrict__ b_msg2,
    const float* __restrict__ W_att, const float* __restrict__ b_att,
    const float* __restrict__ W_pos1, const float* __restrict__ b_pos1,
    const float* __restrict__ W_pos2, const float* __restrict__ b_pos2,
    const float* __restrict__ W_node1, const float* __restrict__ b_node1,
    const float* __restrict__ W_node2, const float* __restrict__ b_node2,
    const float* __restrict__ W_t, const float* __restrict__ b_t,
    float* __restrict__ out)
{
    constexpr int DST  = 128 / NQP;   // dsts per block: 16 or 32
    constexpr int SI   = DST / 8;     // si iterations: 2 or 4
    constexpr int BOFF = DST / 2;     // B-dst offset: 8 or 16
    constexpr int EPP  = DST / 16;    // node-epilogue passes: 1 or 2

    __shared__ unsigned short sHBh[128 * 40];   // 10240 B
    __shared__ float sPx[128], sPy[128];        // 1024 B
    __shared__ __align__(16) unsigned char uraw[14336]; // edge: mbuf+spn / node: sH+nmb
    __shared__ float sAgg[32][36];              // 4608 B (DST rows used)
    __shared__ float2 sAgp[32];                 // 256 B

    unsigned int* mbuf = (unsigned int*)uraw;            // 8*16*20*4 = 10240 B
    float2* spn = (float2*)(uraw + 10240);               // 8*64*8 = 4096 B
    float (*sH)[36] = (float(*)[36])uraw;                // node alias: 2304 B
    unsigned int* nmb = (unsigned int*)(uraw + 2304);    // node alias: 1280 B

    cg::grid_group grid = cg::this_grid();

    const int t = threadIdx.x;
    const int bx = blockIdx.x;
    const int g = bx / NQP, qp = bx % NQP;
    const int gbase = g << 7;

    const int lane = t & 63, w = t >> 6;       // w = 0..3
    const int c = lane & 15, rg = lane >> 4, kk = rg << 3;

    unsigned int* mbA = mbuf + w * 320;
    unsigned int* mbB = mbuf + (w + 4) * 320;

    for (int l = 0; l < L; ++l) {
        const int par = l & 1, op = par ^ 1;

        const float* __restrict__ HAin = ws + (par ? OFF_HA1 : OFF_HA0);
        const unsigned short* __restrict__ HBin =
            (const unsigned short*)(ws + (par ? OFF_HB1 : OFF_HB0));
        const float* __restrict__ Pin = ws + (par ? OFF_P1 : OFF_P0);

        // ---- stage HBh + positions ----
#pragma unroll
        for (int ch = 0; ch < 2; ++ch) {
            const int chunk = t + (ch << 8);
            const int row = chunk >> 2, g4 = chunk & 3;
            *(uint4*)(sHBh + row * 40 + (g4 << 3)) =
                *(const uint4*)(HBin + (gbase + row) * 32 + (g4 << 3));
        }
        if (t < 128) {
            sPx[t] = Pin[(gbase + t) * 2];
            sPy[t] = Pin[(gbase + t) * 2 + 1];
        }
        __syncthreads();

        // ---- resident weight fragments (per layer) ----
        const float* __restrict__ Wm2L = W_msg2 + l * 1024;
        const float* __restrict__ Wp1L = W_pos1 + l * 1024;
        bf16x8 WB1c0, WB1c1, WBpc0, WBpc1, WBac;
#pragma unroll
        for (int j = 0; j < 8; ++j) {
            WB1c0[j] = f2bfs(Wm2L[(kk + j) * 32 + c]);
            WB1c1[j] = f2bfs(Wm2L[(kk + j) * 32 + c + 16]);
            const int pk = ((kk + j) & 1) * 16 + ((kk + j) >> 1);
            WBpc0[j] = f2bfs(Wp1L[pk * 32 + c]);
            WBpc1[j] = f2bfs(Wp1L[pk * 32 + c + 16]);
            WBac[j]  = f2bfs(W_att[l * 32 + pk]);
        }
        float vwr[8];
        {
            const float* wrR = W_msg1 + l * 97 * 32 + 64 * 32 + kk;
#pragma unroll
            for (int j = 0; j < 8; ++j) vwr[j] = wrR[j];
        }
        const float batt  = b_att[l];
        const float vbm20 = b_msg2[l * 32 + c], vbm21 = b_msg2[l * 32 + c + 16];
        const float vbp10 = b_pos1[l * 32 + c], vbp11 = b_pos1[l * 32 + c + 16];
        const float vwp20 = W_pos2[l * 32 + c], vwp21 = W_pos2[l * 32 + c + 16];
        const float bp2   = b_pos2[l];

#pragma unroll 1
        for (int si = 0; si < SI; ++si) {
            const int dlA = (si << 2) + w, dlB = dlA + BOFF;
            const int dlocA = qp * DST + dlA, dlocB = qp * DST + dlB;
            float vhaA[8], vhaB[8];
            {
                const float* haRA = HAin + (gbase + dlocA) * 32 + kk;
                const float* haRB = HAin + (gbase + dlocB) * 32 + kk;
#pragma unroll
                for (int j = 0; j < 8; ++j) { vhaA[j] = haRA[j]; vhaB[j] = haRB[j]; }
            }
            const float pxdA = sPx[dlocA], pydA = sPy[dlocA];
            const float pxdB = sPx[dlocB], pydB = sPy[dlocB];

            float aghc0A = 0.f, aghc1A = 0.f, apxA = 0.f, apyA = 0.f, spnxA = 0.f, spnyA = 0.f;
            float aghc0B = 0.f, aghc1B = 0.f, apxB = 0.f, apyB = 0.f, spnxB = 0.f, spnyB = 0.f;

#pragma unroll 1
            for (int half = 0; half < 2; ++half) {
                const int src = (half << 6) + lane;
                const float sx = sPx[src], sy = sPy[src];
                const float dxA = pxdA - sx, dyA = pydA - sy;
                const float dxB = pxdB - sx, dyB = pydB - sy;
                const float radialA = dxA * dxA + dyA * dyA;
                const float radialB = dxB * dxB + dyB * dyB;
                const float invA = __builtin_amdgcn_rcpf(__builtin_amdgcn_sqrtf(radialA) + 1e-6f);
                const float invB = __builtin_amdgcn_rcpf(__builtin_amdgcn_sqrtf(radialB) + 1e-6f);
                const float pnxA = dxA * invA, pnyA = dyA * invA;
                const float pnxB = dxB * invB, pnyB = dyB * invB;
                spnxA += pnxA; spnyA += pnyA;
                spnxB += pnxB; spnyB += pnyB;
                spn[w * 64 + lane]       = (float2){pnxA, pnyA};
                spn[(w + 4) * 64 + lane] = (float2){pnxB, pnyB};

#pragma unroll
                for (int tt = 0; tt < 4; ++tt) {
                    const float rad_tA = __shfl(radialA, c + (tt << 4));
                    const float rad_tB = __shfl(radialB, c + (tt << 4));
                    uint4 hraw = *(const uint4*)(sHBh + ((half << 6) + c + (tt << 4)) * 40 + kk);
                    const unsigned short* hs = (const unsigned short*)&hraw;
                    float xA[8], xB[8];
#pragma unroll
                    for (int j = 0; j < 8; ++j) {
                        const float hb = bf2f(hs[j]);
                        xA[j] = fsilu(vhaA[j] + hb + rad_tA * vwr[j]);
                        xB[j] = fsilu(vhaB[j] + hb + rad_tB * vwr[j]);
                    }
                    union { unsigned int u[4]; bf16x8 v; } afA, afB;
#pragma unroll
                    for (int d = 0; d < 4; ++d) {
                        afA.u[d] = pk_trunc(xA[2 * d], xA[2 * d + 1]);
                        afB.u[d] = pk_trunc(xB[2 * d], xB[2 * d + 1]);
                    }
                    f32x4 a0A = (f32x4){vbm20, vbm20, vbm20, vbm20};
                    f32x4 a1A = (f32x4){vbm21, vbm21, vbm21, vbm21};
                    f32x4 a0B = a0A, a1B = a1A;
                    a0A = __builtin_amdgcn_mfma_f32_16x16x32_bf16(afA.v, WB1c0, a0A, 0, 0, 0);
                    a1A = __builtin_amdgcn_mfma_f32_16x16x32_bf16(afA.v, WB1c1, a1A, 0, 0, 0);
                    a0B = __builtin_amdgcn_mfma_f32_16x16x32_bf16(afB.v, WB1c0, a0B, 0, 0, 0);
                    a1B = __builtin_amdgcn_mfma_f32_16x16x32_bf16(afB.v, WB1c1, a1B, 0, 0, 0);

                    float s0A[4], s1A[4], s0B[4], s1B[4];
#pragma unroll
                    for (int j = 0; j < 4; ++j) {
                        s0A[j] = fsilu(a0A[j]);
                        s1A[j] = fsilu(a1A[j]);
                        s0B[j] = fsilu(a0B[j]);
                        s1B[j] = fsilu(a1B[j]);
                        mbA[((rg << 2) + j) * 20 + c] = pk_trunc(s0A[j], s1A[j]);
                        mbB[((rg << 2) + j) * 20 + c] = pk_trunc(s0B[j], s1B[j]);
                    }

                    union { uint4 u; bf16x8 v; } qaA, qaB;
                    qaA.u = *(const uint4*)(mbA + c * 20 + (rg << 2));
                    qaB.u = *(const uint4*)(mbB + c * 20 + (rg << 2));
                    f32x4 zaA = (f32x4){batt, batt, batt, batt};
                    f32x4 zaB = zaA;
                    f32x4 z0A = (f32x4){0.f, 0.f, 0.f, 0.f};
                    f32x4 z1A = z0A, z0B = z0A, z1B = z0A;
                    zaA = __builtin_amdgcn_mfma_f32_16x16x32_bf16(qaA.v, WBac,  zaA, 0, 0, 0);
                    z0A = __builtin_amdgcn_mfma_f32_16x16x32_bf16(qaA.v, WBpc0, z0A, 0, 0, 0);
                    z1A = __builtin_amdgcn_mfma_f32_16x16x32_bf16(qaA.v, WBpc1, z1A, 0, 0, 0);
                    zaB = __builtin_amdgcn_mfma_f32_16x16x32_bf16(qaB.v, WBac,  zaB, 0, 0, 0);
                    z0B = __builtin_amdgcn_mfma_f32_16x16x32_bf16(qaB.v, WBpc0, z0B, 0, 0, 0);
                    z1B = __builtin_amdgcn_mfma_f32_16x16x32_bf16(qaB.v, WBpc1, z1B, 0, 0, 0);
#pragma unroll
                    for (int j = 0; j < 4; ++j) {
                        const float attA = fsigmoid(zaA[j]);
                        const float attB = fsigmoid(zaB[j]);
                        aghc0A += attA * s0A[j];
                        aghc1A += attA * s1A[j];
                        aghc0B += attB * s0B[j];
                        aghc1B += attB * s1B[j];
                        const float q0A = fsilu(attA * z0A[j] + vbp10);
                        const float q1A = fsilu(attA * z1A[j] + vbp11);
                        const float q0B = fsilu(attB * z0B[j] + vbp10);
                        const float q1B = fsilu(attB * z1B[j] + vbp11);
                        const float pwpA = q0A * vwp20 + q1A * vwp21;
                        const float pwpB = q0B * vwp20 + q1B * vwp21;
                        const float2 pnA = spn[w * 64 + (tt << 4) + (rg << 2) + j];
                        const float2 pnB = spn[(w + 4) * 64 + (tt << 4) + (rg << 2) + j];
                        apxA += pwpA * pnA.x;
                        apyA += pwpA * pnA.y;
                        apxB += pwpB * pnB.x;
                        apyB += pwpB * pnB.y;
                    }
                }
            }

            // si epilogue: reduce both dsts, stash aggh/aggp (or write out at l=L-1)
            aghc0A += __shfl_xor(aghc0A, 16); aghc0A += __shfl_xor(aghc0A, 32);
            aghc1A += __shfl_xor(aghc1A, 16); aghc1A += __shfl_xor(aghc1A, 32);
            aghc0B += __shfl_xor(aghc0B, 16); aghc0B += __shfl_xor(aghc0B, 32);
            aghc1B += __shfl_xor(aghc1B, 16); aghc1B += __shfl_xor(aghc1B, 32);
#pragma unroll
            for (int off = 1; off < 64; off <<= 1) {
                apxA  += __shfl_xor(apxA, off);
                apyA  += __shfl_xor(apyA, off);
                spnxA += __shfl_xor(spnxA, off);
                spnyA += __shfl_xor(spnyA, off);
                apxB  += __shfl_xor(apxB, off);
                apyB  += __shfl_xor(apyB, off);
                spnxB += __shfl_xor(spnxB, off);
                spnyB += __shfl_xor(spnyB, off);
            }
            if (l < L - 1) {
                if (lane < 32) {
                    sAgg[dlA][lane] = (lane < 16) ? aghc0A : aghc1A;
                    sAgg[dlB][lane] = (lane < 16) ? aghc0B : aghc1B;
                }
                if (lane == 0) {
                    sAgp[dlA] = (float2){(apxA + bp2 * spnxA) * (1.0f / 128.0f),
                                         (apyA + bp2 * spnyA) * (1.0f / 128.0f)};
                    sAgp[dlB] = (float2){(apxB + bp2 * spnxB) * (1.0f / 128.0f),
                                         (apyB + bp2 * spnyB) * (1.0f / 128.0f)};
                }
            } else if (lane == 0) {
                if (dlocA >= NG) {
                    out[(g * NSH + (dlocA - NG)) * 2]     = pxdA + (apxA + bp2 * spnxA) * (1.0f / 128.0f);
                    out[(g * NSH + (dlocA - NG)) * 2 + 1] = pydA + (apyA + bp2 * spnyA) * (1.0f / 128.0f);
                }
                if (dlocB >= NG) {
                    out[(g * NSH + (dlocB - NG)) * 2]     = pxdB + (apxB + bp2 * spnxB) * (1.0f / 128.0f);
                    out[(g * NSH + (dlocB - NG)) * 2 + 1] = pydB + (apyB + bp2 * spnyB) * (1.0f / 128.0f);
                }
            }
        }
        if (l == L - 1) break;                 // out written; no epilogue/sync

        __syncthreads();   // sAgg/sAgp complete; uraw free for node aliases

        // ---------- NODE + pre(l+1) epilogue: single wave, DST nodes ----------
        if (t < 64) {
            float* __restrict__ HAout = ws + (op ? OFF_HA1 : OFF_HA0);
            unsigned short* __restrict__ HBout = (unsigned short*)(ws + (op ? OFF_HB1 : OFF_HB0));
            float* __restrict__ Pout = ws + (op ? OFF_P1 : OFF_P0);

            const float* __restrict__ Wn1 = W_node1 + l * 2048;
            const float* __restrict__ Wn2 = W_node2 + l * 1024;
            const float* __restrict__ W1n = W_msg1 + (l + 1) * 97 * 32;
            bf16x8 B1[2][2], B2[2], Ba[2], Bb[2];
#pragma unroll
            for (int j = 0; j < 8; ++j) {
                const int pk = ((kk + j) & 1) * 16 + ((kk + j) >> 1);
#pragma unroll
                for (int nh = 0; nh < 2; ++nh) {
                    B1[0][nh][j] = f2bfs(Wn1[(kk + j) * 32 + nh * 16 + c]);
                    B1[1][nh][j] = f2bfs(Wn1[(32 + kk + j) * 32 + nh * 16 + c]);
                    B2[nh][j]    = f2bfs(Wn2[pk * 32 + nh * 16 + c]);
                    Ba[nh][j]    = f2bfs(W1n[pk * 32 + nh * 16 + c]);
                    Bb[nh][j]    = f2bfs(W1n[(32 + pk) * 32 + nh * 16 + c]);
                }
            }

            // temb chain (redundant per block; one writer block per graph)
            const int c2 = lane & 31;
            const float* __restrict__ tin = ws + (par ? OFF_TEMB1 : OFF_TEMB0) + g * 32;
            const float* __restrict__ Wt = W_t + l * 1024;
            float a2 = b_t[l * 32 + c2];
#pragma unroll
            for (int k = 0; k < 32; ++k) a2 += tin[k] * Wt[k * 32 + c2];
            const float tnew = fsilu(a2);
            float tv = b_msg1[(l + 1) * 32 + c2];
#pragma unroll
            for (int k = 0; k < 32; ++k) tv += __shfl(tnew, k) * W1n[(65 + k) * 32 + c2];
            if (qp == 0 && lane < 32)
                ws[(par ? OFF_TEMB0 : OFF_TEMB1) + g * 32 + lane] = tnew;
            const float tv0 = __shfl(tv, c), tv1 = __shfl(tv, c + 16);

#pragma unroll 1
            for (int ep = 0; ep < EPP; ++ep) {
                const int nbase = bx * DST + (ep << 4);

                // stage h (16 rows x 32 f32)
                {
                    const int row = lane >> 2, seg = lane & 3;
                    const float* hsrc = ws + OFF_H + (nbase + row) * 32 + (seg << 3);
#pragma unroll
                    for (int j = 0; j < 8; ++j) sH[row][(seg << 3) + j] = hsrc[j];
                }

                // GEMM1: [h | aggh] @ Wn1
                union { unsigned int u[4]; bf16x8 v; } A0, A1;
#pragma unroll
                for (int d = 0; d < 4; ++d) {
                    A0.u[d] = pk_trunc(sH[c][kk + 2 * d], sH[c][kk + 2 * d + 1]);
                    A1.u[d] = pk_trunc(sAgg[(ep << 4) + c][kk + 2 * d],
                                       sAgg[(ep << 4) + c][kk + 2 * d + 1]);
                }
                f32x4 u1[2];
#pragma unroll
                for (int nh = 0; nh < 2; ++nh) {
                    const float bb = b_node1[l * 32 + nh * 16 + c];
                    f32x4 acc = (f32x4){bb, bb, bb, bb};
                    acc = __builtin_amdgcn_mfma_f32_16x16x32_bf16(A0.v, B1[0][nh], acc, 0, 0, 0);
                    acc = __builtin_amdgcn_mfma_f32_16x16x32_bf16(A1.v, B1[1][nh], acc, 0, 0, 0);
                    u1[nh] = acc;
                }

                // GEMM2
#pragma unroll
                for (int j = 0; j < 4; ++j)
                    nmb[((rg << 2) + j) * 20 + c] = pk_trunc(fsilu(u1[0][j]), fsilu(u1[1][j]));
                union { uint4 q; bf16x8 v; } qa;
                qa.q = *(const uint4*)(nmb + c * 20 + (rg << 2));
                f32x4 u2[2];
#pragma unroll
                for (int nh = 0; nh < 2; ++nh) {
                    const float bb = b_node2[l * 32 + nh * 16 + c];
                    f32x4 acc = (f32x4){bb, bb, bb, bb};
                    u2[nh] = __builtin_amdgcn_mfma_f32_16x16x32_bf16(qa.v, B2[nh], acc, 0, 0, 0);
                }

                // h' = leaky + residual; store + pi-stage
                float hp0[4], hp1[4];
#pragma unroll
                for (int j = 0; j < 4; ++j) {
                    const int row = (rg << 2) + j;
                    const float h0 = sH[row][c], h1 = sH[row][c + 16];
                    const float v0 = u2[0][j], v1 = u2[1][j];
                    hp0[j] = (v0 > 0.f ? v0 : 0.01f * v0) + h0;
                    hp1[j] = (v1 > 0.f ? v1 : 0.01f * v1) + h1;
                    ws[OFF_H + (nbase + row) * 32 + c]      = hp0[j];
                    ws[OFF_H + (nbase + row) * 32 + c + 16] = hp1[j];
                    nmb[row * 20 + c] = pk_trunc(hp0[j], hp1[j]);
                }

                // fused pre(l+1): HA/HB via MFMA -> opposite-parity buffers
                qa.q = *(const uint4*)(nmb + c * 20 + (rg << 2));
                f32x4 ha[2], hb[2];
                {
                    f32x4 zz = (f32x4){0.f, 0.f, 0.f, 0.f};
#pragma unroll
                    for (int nh = 0; nh < 2; ++nh) {
                        ha[nh] = __builtin_amdgcn_mfma_f32_16x16x32_bf16(qa.v, Ba[nh], zz, 0, 0, 0);
                        hb[nh] = __builtin_amdgcn_mfma_f32_16x16x32_bf16(qa.v, Bb[nh], zz, 0, 0, 0);
                    }
                }
#pragma unroll
                for (int j = 0; j < 4; ++j) {
                    const int node = nbase + (rg << 2) + j;
                    HAout[node * 32 + c]      = ha[0][j] + tv0;
                    HAout[node * 32 + c + 16] = ha[1][j] + tv1;
                    HBout[node * 32 + c]      = (unsigned short)f2bfs(hb[0][j]);
                    HBout[node * 32 + c + 16] = (unsigned short)f2bfs(hb[1][j]);
                }

                // p' = p + aggp -> opposite-parity buffer
                if (lane < 32) {
                    const int dl2 = lane >> 1, d = lane & 1;
                    const int node = nbase + dl2;
                    const float ag = d ? sAgp[(ep << 4) + dl2].y : sAgp[(ep << 4) + dl2].x;
                    Pout[node * 2 + d] = (par ? ws[OFF_P1 + node * 2 + d]
                                              : ws[OFF_P0 + node * 2 + d]) + ag;
                }
            }
        }

        grid.sync();   // all blocks' HA/HB/P/temb/H writes visible for layer l+1
    }
}

// ---------------- fallback per-layer kernel (R4 verbatim, proven 43.1us) ----------------
// 1024 blocks x 256 thr; block = (graph, 8 dsts); each wave owns TWO dsts.
__global__ __attribute__((amdgpu_flat_work_group_size(256, 256)))
__attribute__((amdgpu_waves_per_eu(2, 4))) void edge_kernel(
    float* __restrict__ ws,
    const float* __restrict__ W_msg1, const float* __restrict__ b_msg1,
    const float* __restrict__ W_msg2, const float* __restrict__ b_msg2,
    const float* __restrict__ W_att, const float* __restrict__ b_att,
    const float* __restrict__ W_pos1, const float* __restrict__ b_pos1,
    const float* __restrict__ W_pos2, const float* __restrict__ b_pos2,
    const float* __restrict__ W_node1, const float* __restrict__ b_node1,
    const float* __restrict__ W_node2, const float* __restrict__ b_node2,
    const float* __restrict__ W_t, const float* __restrict__ b_t,
    float* __restrict__ out, int l)
{
    __shared__ unsigned short sHBh[128 * 40];
    __shared__ float sPx[128], sPy[128];
    __shared__ __align__(16) unsigned char uraw[14336];
    __shared__ float sAgg[16][36];
    __shared__ float2 sAgp[16];

    unsigned int* mbuf = (unsigned int*)uraw;
    float2* spn = (float2*)(uraw + 10240);
    float (*sH)[36] = (float(*)[36])uraw;
    unsigned int* nmb = (unsigned int*)(uraw + 2304);

    const int t = threadIdx.x;
    const int bx = blockIdx.x;
    const int g = bx >> 4, qp = bx & 15;
    const int gbase = g << 7;
    const int par = l & 1, op = (l + 1) & 1;

    const float* __restrict__ HAin = ws + (par ? OFF_HA1 : OFF_HA0);
    const unsigned short* __restrict__ HBin = (const unsigned short*)(ws + (par ? OFF_HB1 : OFF_HB0));
    const float* __restrict__ Pin = ws + (par ? OFF_P1 : OFF_P0);

#pragma unroll
    for (int ch = 0; ch < 2; ++ch) {
        const int chunk = t + (ch << 8);
        const int row = chunk >> 2, g4 = chunk & 3;
        *(uint4*)(sHBh + row * 40 + (g4 << 3)) =
            *(const uint4*)(HBin + (gbase + row) * 32 + (g4 << 3));
    }
    if (t < 128) {
        sPx[t] = Pin[(gbase + t) * 2];
        sPy[t] = Pin[(gbase + t) * 2 + 1];
    }
    __syncthreads();

    const int lane = t & 63, w = t >> 6;
    const int c = lane & 15, rg = lane >> 4, kk = rg << 3;

    const float* __restrict__ Wm2L = W_msg2 + l * 1024;
    const float* __restrict__ Wp1L = W_pos1 + l * 1024;
    bf16x8 WB1c0, WB1c1, WBpc0, WBpc1, WBac;
#pragma unroll
    for (int j = 0; j < 8; ++j) {
        WB1c0[j] = f2bfs(Wm2L[(kk + j) * 32 + c]);
        WB1c1[j] = f2bfs(Wm2L[(kk + j) * 32 + c + 16]);
        const int pk = ((kk + j) & 1) * 16 + ((kk + j) >> 1);
        WBpc0[j] = f2bfs(Wp1L[pk * 32 + c]);
        WBpc1[j] = f2bfs(Wp1L[pk * 32 + c + 16]);
        WBac[j]  = f2bfs(W_att[l * 32 + pk]);
    }
    float vwr[8];
    {
        const float* wrR = W_msg1 + l * 97 * 32 + 64 * 32 + kk;
#pragma unroll
        for (int j = 0; j < 8; ++j) vwr[j] = wrR[j];
    }
    const float batt  = b_att[l];
    const float vbm20 = b_msg2[l * 32 + c], vbm21 = b_msg2[l * 32 + c + 16];
    const float vbp10 = b_pos1[l * 32 + c], vbp11 = b_pos1[l * 32 + c + 16];
    const float vwp20 = W_pos2[l * 32 + c], vwp21 = W_pos2[l * 32 + c + 16];
    const float bp2   = b_pos2[l];

    unsigned int* mbA = mbuf + w * 320;
    unsigned int* mbB = mbuf + (w + 4) * 320;

    const int dlA = w, dlB = w + 4;
    const int dlocA = (qp << 3) + dlA, dlocB = (qp << 3) + dlB;
    float vhaA[8], vhaB[8];
    {
        const float* haRA = HAin + (gbase + dlocA) * 32 + kk;
        const float* haRB = HAin + (gbase + dlocB) * 32 + kk;
#pragma unroll
        for (int j = 0; j < 8; ++j) { vhaA[j] = haRA[j]; vhaB[j] = haRB[j]; }
    }
    const float pxdA = sPx[dlocA], pydA = sPy[dlocA];
    const float pxdB = sPx[dlocB], pydB = sPy[dlocB];

    float aghc0A = 0.f, aghc1A = 0.f, apxA = 0.f, apyA = 0.f, spnxA = 0.f, spnyA = 0.f;
    float aghc0B = 0.f, aghc1B = 0.f, apxB = 0.f, apyB = 0.f, spnxB = 0.f, spnyB = 0.f;

#pragma unroll 1
    for (int half = 0; half < 2; ++half) {
        const int src = (half << 6) + lane;
        const float sx = sPx[src], sy = sPy[src];
        const float dxA = pxdA - sx, dyA = pydA - sy;
        const float dxB = pxdB - sx, dyB = pydB - sy;
        const float radialA = dxA * dxA + dyA * dyA;
        const float radialB = dxB * dxB + dyB * dyB;
        const float invA = __builtin_amdgcn_rcpf(__builtin_amdgcn_sqrtf(radialA) + 1e-6f);
        const float invB = __builtin_amdgcn_rcpf(__builtin_amdgcn_sqrtf(radialB) + 1e-6f);
        const float pnxA = dxA * invA, pnyA = dyA * invA;
        const float pnxB = dxB * invB, pnyB = dyB * invB;
        spnxA += pnxA; spnyA += pnyA;
        spnxB += pnxB; spnyB += pnyB;
        spn[w * 64 + lane]       = (float2){pnxA, pnyA};
        spn[(w + 4) * 64 + lane] = (float2){pnxB, pnyB};

#pragma unroll
        for (int tt = 0; tt < 4; ++tt) {
            const float rad_tA = __shfl(radialA, c + (tt << 4));
            const float rad_tB = __shfl(radialB, c + (tt << 4));
            uint4 hraw = *(const uint4*)(sHBh + ((half << 6) + c + (tt << 4)) * 40 + kk);
            const unsigned short* hs = (const unsigned short*)&hraw;
            float xA[8], xB[8];
#pragma unroll
            for (int j = 0; j < 8; ++j) {
                const float hb = bf2f(hs[j]);
                xA[j] = fsilu(vhaA[j] + hb + rad_tA * vwr[j]);
                xB[j] = fsilu(vhaB[j] + hb + rad_tB * vwr[j]);
            }
            union { unsigned int u[4]; bf16x8 v; } afA, afB;
#pragma unroll
            for (int d = 0; d < 4; ++d) {
                afA.u[d] = pk_trunc(xA[2 * d], xA[2 * d + 1]);
                afB.u[d] = pk_trunc(xB[2 * d], xB[2 * d + 1]);
            }
            f32x4 a0A = (f32x4){vbm20, vbm20, vbm20, vbm20};
            f32x4 a1A = (f32x4){vbm21, vbm21, vbm21, vbm21};
            f32x4 a0B = a0A, a1B = a1A;
            a0A = __builtin_amdgcn_mfma_f32_16x16x32_bf16(afA.v, WB1c0, a0A, 0, 0, 0);
            a1A = __builtin_amdgcn_mfma_f32_16x16x32_bf16(afA.v, WB1c1, a1A, 0, 0, 0);
            a0B = __builtin_amdgcn_mfma_f32_16x16x32_bf16(afB.v, WB1c0, a0B, 0, 0, 0);
            a1B = __builtin_amdgcn_mfma_f32_16x16x32_bf16(afB.v, WB1c1, a1B, 0, 0, 0);

            float s0A[4], s1A[4], s0B[4], s1B[4];
#pragma unroll
            for (int j = 0; j < 4; ++j) {
                s0A[j] = fsilu(a0A[j]);
                s1A[j] = fsilu(a1A[j]);
                s0B[j] = fsilu(a0B[j]);
                s1B[j] = fsilu(a1B[j]);
                mbA[((rg << 2) + j) * 20 + c] = pk_trunc(s0A[j], s1A[j]);
                mbB[((rg << 2) + j) * 20 + c] = pk_trunc(s0B[j], s1B[j]);
            }

            union { uint4 u; bf16x8 v; } qaA, qaB;
            qaA.u = *(const uint4*)(mbA + c * 20 + (rg << 2));
            qaB.u = *(const uint4*)(mbB + c * 20 + (rg << 2));
            f32x4 zaA = (f32x4){batt, batt, batt, batt};
            f32x4 zaB = zaA;
            f32x4 z0A = (f32x4){0.f, 0.f, 0.f, 0.f};
            f32x4 z1A = z0A, z0B = z0A, z1B = z0A;
            zaA = __builtin_amdgcn_mfma_f32_16x16x32_bf16(qaA.v, WBac,  zaA, 0, 0, 0);
            z0A = __builtin_amdgcn_mfma_f32_16x16x32_bf16(qaA.v, WBpc0, z0A, 0, 0, 0);
            z1A = __builtin_amdgcn_mfma_f32_16x16x32_bf16(qaA.v, WBpc1, z1A, 0, 0, 0);
            zaB = __builtin_amdgcn_mfma_f32_16x16x32_bf16(qaB.v, WBac,  zaB, 0, 0, 0);
            z0B = __builtin_amdgcn_mfma_f32_16x16x32_bf16(qaB.v, WBpc0, z0B, 0, 0, 0);
            z1B = __builtin_amdgcn_mfma_f32_16x16x32_bf16(qaB.v, WBpc1, z1B, 0, 0, 0);
#pragma unroll
            for (int j = 0; j < 4; ++j) {
                const float attA = fsigmoid(zaA[j]);
                const float attB = fsigmoid(zaB[j]);
                aghc0A += attA * s0A[j];
                aghc1A += attA * s1A[j];
                aghc0B += attB * s0B[j];
                aghc1B += attB * s1B[j];
                const float q0A = fsilu(attA * z0A[j] + vbp10);
                const float q1A = fsilu(attA * z1A[j] + vbp11);
                const float q0B = fsilu(attB * z0B[j] + vbp10);
                const float q1B = fsilu(attB * z1B[j] + vbp11);
                const float pwpA = q0A * vwp20 + q1A * vwp21;
                const float pwpB = q0B * vwp20 + q1B * vwp21;
                const float2 pnA = spn[w * 64 + (tt << 4) + (rg << 2) + j];
                const float2 pnB = spn[(w + 4) * 64 + (tt << 4) + (rg << 2) + j];
                apxA += pwpA * pnA.x;
                apyA += pwpA * pnA.y;
                apxB += pwpB * pnB.x;
                apyB += pwpB * pnB.y;
            }
        }
    }

    aghc0A += __shfl_xor(aghc0A, 16); aghc0A += __shfl_xor(aghc0A, 32);
    aghc1A += __shfl_xor(aghc1A, 16); aghc1A += __shfl_xor(aghc1A, 32);
    aghc0B += __shfl_xor(aghc0B, 16); aghc0B += __shfl_xor(aghc0B, 32);
    aghc1B += __shfl_xor(aghc1B, 16); aghc1B += __shfl_xor(aghc1B, 32);
#pragma unroll
    for (int off = 1; off < 64; off <<= 1) {
        apxA  += __shfl_xor(apxA, off);
        apyA  += __shfl_xor(apyA, off);
        spnxA += __shfl_xor(spnxA, off);
        spnyA += __shfl_xor(spnyA, off);
        apxB  += __shfl_xor(apxB, off);
        apyB  += __shfl_xor(apyB, off);
        spnxB += __shfl_xor(spnxB, off);
        spnyB += __shfl_xor(spnyB, off);
    }
    if (l < L - 1) {
        if (lane < 32) {
            sAgg[dlA][lane] = (lane < 16) ? aghc0A : aghc1A;
            sAgg[dlB][lane] = (lane < 16) ? aghc0B : aghc1B;
        }
        if (lane == 0) {
            sAgp[dlA] = (float2){(apxA + bp2 * spnxA) * (1.0f / 128.0f),
                                 (apyA + bp2 * spnyA) * (1.0f / 128.0f)};
            sAgp[dlB] = (float2){(apxB + bp2 * spnxB) * (1.0f / 128.0f),
                                 (apyB + bp2 * spnyB) * (1.0f / 128.0f)};
        }
    } else if (lane == 0) {
        if (dlocA >= NG) {
            out[(g * NSH + (dlocA - NG)) * 2]     = pxdA + (apxA + bp2 * spnxA) * (1.0f / 128.0f);
            out[(g * NSH + (dlocA - NG)) * 2 + 1] = pydA + (apyA + bp2 * spnyA) * (1.0f / 128.0f);
        }
        if (dlocB >= NG) {
            out[(g * NSH + (dlocB - NG)) * 2]     = pxdB + (apxB + bp2 * spnxB) * (1.0f / 128.0f);
            out[(g * NSH + (dlocB - NG)) * 2 + 1] = pydB + (apyB + bp2 * spnyB) * (1.0f / 128.0f);
        }
    }
    if (l == L - 1) return;

    __syncthreads();

    if (t < 64) {
        const int nbase = bx << 3;
        float* __restrict__ HAout = ws + (op ? OFF_HA1 : OFF_HA0);
        unsigned short* __restrict__ HBout = (unsigned short*)(ws + (op ? OFF_HB1 : OFF_HB0));
        float* __restrict__ Pout = ws + (op ? OFF_P1 : OFF_P0);

        {
            const int row8 = lane >> 3, seg = lane & 7;
            const float* hsrc = ws + OFF_H + (nbase + row8) * 32 + (seg << 2);
#pragma unroll
            for (int j = 0; j < 4; ++j) sH[row8][(seg << 2) + j] = hsrc[j];
        }

        const float* __restrict__ Wn1 = W_node1 + l * 2048;
        const float* __restrict__ Wn2 = W_node2 + l * 1024;
        const float* __restrict__ W1  = W_msg1 + (l + 1) * 97 * 32;
        bf16x8 B1[2][2], B2[2], Ba[2], Bb[2];
#pragma unroll
        for (int j = 0; j < 8; ++j) {
            const int pk = ((kk + j) & 1) * 16 + ((kk + j) >> 1);
#pragma unroll
            for (int nh = 0; nh < 2; ++nh) {
                B1[0][nh][j] = f2bfs(Wn1[(kk + j) * 32 + nh * 16 + c]);
                B1[1][nh][j] = f2bfs(Wn1[(32 + kk + j) * 32 + nh * 16 + c]);
                B2[nh][j]    = f2bfs(Wn2[pk * 32 + nh * 16 + c]);
                Ba[nh][j]    = f2bfs(W1[pk * 32 + nh * 16 + c]);
                Bb[nh][j]    = f2bfs(W1[(32 + pk) * 32 + nh * 16 + c]);
            }
        }

        const int c2 = lane & 31;
        const float* __restrict__ tin = ws + (par ? OFF_TEMB1 : OFF_TEMB0) + g * 32;
        const float* __restrict__ Wt = W_t + l * 1024;
        float a2 = b_t[l * 32 + c2];
#pragma unroll
        for (int k = 0; k < 32; ++k) a2 += tin[k] * Wt[k * 32 + c2];
        const float tnew = fsilu(a2);
        float tv = b_msg1[(l + 1) * 32 + c2];
#pragma unroll
        for (int k = 0; k < 32; ++k) tv += __shfl(tnew, k) * W1[(65 + k) * 32 + c2];
        if ((bx & 15) == 0 && lane < 32)
            ws[(par ? OFF_TEMB0 : OFF_TEMB1) + g * 32 + lane] = tnew;

        union { unsigned int u[4]; bf16x8 v; } A0, A1;
#pragma unroll
        for (int d = 0; d < 4; ++d) {
            A0.u[d] = pk_trunc(sH[c][kk + 2 * d],   sH[c][kk + 2 * d + 1]);
            A1.u[d] = pk_trunc(sAgg[c][kk + 2 * d], sAgg[c][kk + 2 * d + 1]);
        }
        f32x4 u1[2];
#pragma unroll
        for (int nh = 0; nh < 2; ++nh) {
            const float bb = b_node1[l * 32 + nh * 16 + c];
            f32x4 acc = (f32x4){bb, bb, bb, bb};
            acc = __builtin_amdgcn_mfma_f32_16x16x32_bf16(A0.v, B1[0][nh], acc, 0, 0, 0);
            acc = __builtin_amdgcn_mfma_f32_16x16x32_bf16(A1.v, B1[1][nh], acc, 0, 0, 0);
            u1[nh] = acc;
        }

#pragma unroll
        for (int j = 0; j < 4; ++j)
            nmb[((rg << 2) + j) * 20 + c] = pk_trunc(fsilu(u1[0][j]), fsilu(u1[1][j]));
        union { uint4 q; bf16x8 v; } qa;
        qa.q = *(const uint4*)(nmb + c * 20 + (rg << 2));
        f32x4 u2[2];
#pragma unroll
        for (int nh = 0; nh < 2; ++nh) {
            const float bb = b_node2[l * 32 + nh * 16 + c];
            f32x4 acc = (f32x4){bb, bb, bb, bb};
            u2[nh] = __builtin_amdgcn_mfma_f32_16x16x32_bf16(qa.v, B2[nh], acc, 0, 0, 0);
        }

        float hp0[4], hp1[4];
#pragma unroll
        for (int j = 0; j < 4; ++j) {
            const int row = (rg << 2) + j;
            const float h0 = sH[row][c], h1 = sH[row][c + 16];
            const float v0 = u2[0][j], v1 = u2[1][j];
            hp0[j] = (v0 > 0.f ? v0 : 0.01f * v0) + h0;
            hp1[j] = (v1 > 0.f ? v1 : 0.01f * v1) + h1;
            if (row < 8) {
                ws[OFF_H + (nbase + row) * 32 + c]      = hp0[j];
                ws[OFF_H + (nbase + row) * 32 + c + 16] = hp1[j];
            }
            nmb[row * 20 + c] = pk_trunc(hp0[j], hp1[j]);
        }

        qa.q = *(const uint4*)(nmb + c * 20 + (rg << 2));
        f32x4 ha[2], hb[2];
        {
            f32x4 zz = (f32x4){0.f, 0.f, 0.f, 0.f};
#pragma unroll
            for (int nh = 0; nh < 2; ++nh) {
                ha[nh] = __builtin_amdgcn_mfma_f32_16x16x32_bf16(qa.v, Ba[nh], zz, 0, 0, 0);
                hb[nh] = __builtin_amdgcn_mfma_f32_16x16x32_bf16(qa.v, Bb[nh], zz, 0, 0, 0);
            }
        }
        const float tv0 = __shfl(tv, c), tv1 = __shfl(tv, c + 16);
#pragma unroll
        for (int j = 0; j < 4; ++j) {
            const int row = (rg << 2) + j;
            if (row < 8) {
                const int node = nbase + row;
                HAout[node * 32 + c]      = ha[0][j] + tv0;
                HAout[node * 32 + c + 16] = ha[1][j] + tv1;
                HBout[node * 32 + c]      = (unsigned short)f2bfs(hb[0][j]);
                HBout[node * 32 + c + 16] = (unsigned short)f2bfs(hb[1][j]);
            }
        }

        if (lane < 16) {
            const int dl2 = lane >> 1, d = lane & 1;
            const int node = nbase + dl2;
            const float ag = d ? sAgp[dl2].y : sAgp[dl2].x;
            Pout[node * 2 + d] = (par ? ws[OFF_P1 + node * 2 + d]
                                      : ws[OFF_P0 + node * 2 + d]) + ag;
        }
    }
}

// ---------------- launch ----------------
extern "C" void kernel_launch(void* const* d_in, const int* in_sizes, int n_in,
                              void* d_out, int out_size, void* d_ws, size_t ws_size,
                              hipStream_t stream)
{
    const float* pos      = (const float*)d_in[0];
    const int*   tsteps   = (const int*)d_in[1];
    const float* goal_pos = (const float*)d_in[2];
    const float* W_hin    = (const float*)d_in[3];
    const float* b_hin    = (const float*)d_in[4];
    const float* W_msg1   = (const float*)d_in[5];
    const float* b_msg1   = (const float*)d_in[6];
    const float* W_msg2   = (const float*)d_in[7];
    const float* b_msg2   = (const float*)d_in[8];
    const float* W_att    = (const float*)d_in[9];
    const float* b_att    = (const float*)d_in[10];
    const float* W_pos1   = (const float*)d_in[11];
    const float* b_pos1   = (const float*)d_in[12];
    const float* W_pos2   = (const float*)d_in[13];
    const float* b_pos2   = (const float*)d_in[14];
    const float* W_node1  = (const float*)d_in[15];
    const float* b_node1  = (const float*)d_in[16];
    const float* W_node2  = (const float*)d_in[17];
    const float* b_node2  = (const float*)d_in[18];
    const float* W_t      = (const float*)d_in[19];
    const float* b_t      = (const float*)d_in[20];

    float* ws   = (float*)d_ws;
    float* outp = (float*)d_out;

    setup_pre_kernel<<<1024, 256, 0, stream>>>(ws, pos, tsteps, goal_pos,
                                               W_hin, b_hin, W_msg1, b_msg1);

    void* args[] = {
        (void*)&ws,
        (void*)&W_msg1, (void*)&b_msg1, (void*)&W_msg2, (void*)&b_msg2,
        (void*)&W_att,  (void*)&b_att,  (void*)&W_pos1, (void*)&b_pos1,
        (void*)&W_pos2, (void*)&b_pos2, (void*)&W_node1,(void*)&b_node1,
        (void*)&W_node2,(void*)&b_node2,(void*)&W_t,    (void*)&b_t,
        (void*)&outp
    };

    bool launched = false;

    // Prefer 512-block fused (2 blocks/CU) only if runtime says it co-resides.
    int maxb8 = 0;
    if (hipOccupancyMaxActiveBlocksPerMultiprocessor(&maxb8, fused_layers_kernel<8>,
                                                     256, 0) == hipSuccess && maxb8 >= 2) {
        launched = hipLaunchCooperativeKernel(fused_layers_kernel<8>, dim3(512), dim3(256),
                                              args, 0, stream) == hipSuccess;
    }
    if (!launched) {
        int maxb4 = 0;
        if (hipOccupancyMaxActiveBlocksPerMultiprocessor(&maxb4, fused_layers_kernel<4>,
                                                         256, 0) == hipSuccess && maxb4 >= 1) {
            launched = hipLaunchCooperativeKernel(fused_layers_kernel<4>, dim3(256), dim3(256),
                                                  args, 0, stream) == hipSuccess;
        }
    }
    if (!launched) {
        // proven R4 path (43.1us/layer, passed)
        for (int l = 0; l < L; ++l)
            edge_kernel<<<1024, 256, 0, stream>>>(ws, W_msg1, b_msg1, W_msg2, b_msg2,
                                                  W_att, b_att, W_pos1, b_pos1,
                                                  W_pos2, b_pos2, W_node1, b_node1,
                                                  W_node2, b_node2, W_t, b_t,
                                                  outp, l);
    }
}

// Round 8
// 290.191 us; speedup vs baseline: 1.7622x; 1.7622x over previous
//
#include <hip/hip_runtime.h>
#include <hip/hip_bf16.h>

// ---------------- problem constants ----------------
constexpr int B = 64;
constexpr int NG = 16;
constexpr int NSH = 112;
constexpr int N = 128;          // nodes per graph
constexpr int NN = B * N;       // 8192 total nodes
constexpr int L = 5;

// ---------------- workspace layout (float offsets), double-buffered ----------------
constexpr int OFF_H     = 0;                    // [8192][32] f32 (owner-block access only)
constexpr int OFF_P0    = OFF_H + NN * 32;      // [8192][2]  f32
constexpr int OFF_P1    = OFF_P0 + NN * 2;
constexpr int OFF_TEMB0 = OFF_P1 + NN * 2;      // [64][32]
constexpr int OFF_TEMB1 = OFF_TEMB0 + B * 32;
constexpr int OFF_HA0   = OFF_TEMB1 + B * 32;   // [8192][32] f32
constexpr int OFF_HA1   = OFF_HA0 + NN * 32;
constexpr int OFF_HB0   = OFF_HA1 + NN * 32;    // [8192][32] ushort bf16 (NN*16 floats)
constexpr int OFF_HB1   = OFF_HB0 + NN * 16;

typedef __attribute__((ext_vector_type(8))) short bf16x8;
typedef __attribute__((ext_vector_type(4))) float f32x4;

// ---------------- math helpers ----------------
__device__ __forceinline__ float fsigmoid(float x) {
    return __builtin_amdgcn_rcpf(1.0f + __expf(-x));
}
__device__ __forceinline__ float fsilu(float x) { return x * fsigmoid(x); }
__device__ __forceinline__ short f2bfs(float f) {           // RNE
    union { __hip_bfloat16 b; short s; } u; u.b = __float2bfloat16(f); return u.s;
}
__device__ __forceinline__ float bf2f(unsigned short u) {
    union { unsigned int i; float f; } v; v.i = ((unsigned int)u) << 16; return v.f;
}
// single-inst truncation pack: dst = bf16(hi)<<16 | bf16(lo)
__device__ __forceinline__ unsigned int pk_trunc(float lo, float hi) {
    union { float f; unsigned int u; } a, b;
    a.f = hi; b.f = lo;
    return __builtin_amdgcn_perm(a.u, b.u, 0x07060302u);
}

// ---------------- setup + pre(layer 0): h, p, temb0, HA0, HB0 ----------------
// 1024 blocks x 256 thr; block = 8 nodes of one graph.
__global__ __launch_bounds__(256) void setup_pre_kernel(
    float* __restrict__ ws,
    const float* __restrict__ pos, const int* __restrict__ tsteps,
    const float* __restrict__ goal_pos,
    const float* __restrict__ W_hin, const float* __restrict__ b_hin,
    const float* __restrict__ W_msg1, const float* __restrict__ b_msg1)
{
    __shared__ float sT[32];
    const int t = threadIdx.x, bx = blockIdx.x;
    const int tid = bx * 256 + t;              // 0..262143 == NN*32
    const int c = tid & 31, node = tid >> 5, g = node >> 7, local = node & 127;
    const int row = (local < NG) ? 0 : 1;

    if (t < 32) {                              // temb for this block's graph
        const float tf = (float)tsteps[g];
        const int jj = (t < 16) ? t : (t - 16);
        const float ang = tf * expf(-logf(10000.0f) * (float)jj / 16.0f);
        sT[t] = (t < 16) ? cosf(ang) : sinf(ang);
    }
    __syncthreads();
    if ((bx & 15) == 0 && t < 32) ws[OFF_TEMB0 + g * 32 + t] = sT[t];

    ws[OFF_H + tid] = W_hin[row * 32 + c] + b_hin[c];     // h init

    if (tid < NN * 2) {                        // p init -> P0
        const int d = tid & 1, nd = tid >> 1, g0 = nd >> 7, loc = nd & 127;
        ws[OFF_P0 + tid] = (loc < NG) ? goal_pos[loc * 2 + d]
                                      : pos[(g0 * NSH + (loc - NG)) * 2 + d];
    }

    // pre layer 0 (h is type-determined: W_hin row + b_hin)
    const float* __restrict__ W1 = W_msg1;
    float accA = b_msg1[c], accB = 0.f;
#pragma unroll
    for (int k = 0; k < 32; ++k) {
        const float hk = W_hin[row * 32 + k] + b_hin[k];
        accA += hk * W1[k * 32 + c];
        accB += hk * W1[(32 + k) * 32 + c];
    }
#pragma unroll
    for (int k = 0; k < 32; ++k)
        accA += sT[k] * W1[(65 + k) * 32 + c];
    ws[OFF_HA0 + tid] = accA;
    ((unsigned short*)(ws + OFF_HB0))[tid] = (unsigned short)f2bfs(accB);
}

// ---------------- fused edge + node + pre(l+1) kernel ----------------
// 1024 blocks x 256 thr (4 waves); block = (graph, 8 dsts); each wave owns
// TWO dsts (w and w+4) processed simultaneously (R4 structure, proven 43.1us).
// R7 lesson: cooperative 5-layer fusion PASSED but grid.sync() costs ~60us
// each on MI355X (L2 writeback across 8 XCDs: WRITE_SIZE 13->45MB, 454us
// total) — multi-dispatch with ~10us gaps is strictly cheaper. Reverted.
// R0-R5 lessons: occupancy/grid/ILP/fattening levers all null (43-49us).
// NEW in this round: s_setprio(1) around MFMA clusters (T5) — helps
// independent-wave kernels (+4-7% on attn-like shapes); our waves are
// barrier-free in the main loop, so scheduler can favor MFMA-entering waves.
// waves_per_eu kept at (2,4): R1 lesson — min 4 forced VGPR=64 + spill.
__global__ __attribute__((amdgpu_flat_work_group_size(256, 256)))
__attribute__((amdgpu_waves_per_eu(2, 4))) void edge_kernel(
    float* __restrict__ ws,
    const float* __restrict__ W_msg1, const float* __restrict__ b_msg1,
    const float* __restrict__ W_msg2, const float* __restrict__ b_msg2,
    const float* __restrict__ W_att, const float* __restrict__ b_att,
    const float* __restrict__ W_pos1, const float* __restrict__ b_pos1,
    const float* __restrict__ W_pos2, const float* __restrict__ b_pos2,
    const float* __restrict__ W_node1, const float* __restrict__ b_node1,
    const float* __restrict__ W_node2, const float* __restrict__ b_node2,
    const float* __restrict__ W_t, const float* __restrict__ b_t,
    float* __restrict__ out, int l)
{
    __shared__ unsigned short sHBh[128 * 40];   // 10240 B
    __shared__ float sPx[128], sPy[128];        // 1024 B
    __shared__ __align__(16) unsigned char uraw[14336]; // edge: mbuf+spn / node: sH+nmb
    __shared__ float sAgg[16][36];              // 2304 B (8 rows used)
    __shared__ float2 sAgp[16];                 // 128 B (8 used)

    unsigned int* mbuf = (unsigned int*)uraw;            // 8*16*20*4 = 10240 B
    float2* spn = (float2*)(uraw + 10240);               // 8*64*8 = 4096 B
    float (*sH)[36] = (float(*)[36])uraw;                // node alias: 2304 B
    unsigned int* nmb = (unsigned int*)(uraw + 2304);    // node alias: 1280 B

    const int t = threadIdx.x;
    const int bx = blockIdx.x;                 // 0..1023
    const int g = bx >> 4, qp = bx & 15;
    const int gbase = g << 7;
    const int par = l & 1, op = (l + 1) & 1;

    const float* __restrict__ HAin = ws + (par ? OFF_HA1 : OFF_HA0);
    const unsigned short* __restrict__ HBin = (const unsigned short*)(ws + (par ? OFF_HB1 : OFF_HB0));
    const float* __restrict__ Pin = ws + (par ? OFF_P1 : OFF_P0);

    // ---- stage HBh + positions ----
#pragma unroll
    for (int ch = 0; ch < 2; ++ch) {
        const int chunk = t + (ch << 8);
        const int row = chunk >> 2, g4 = chunk & 3;
        *(uint4*)(sHBh + row * 40 + (g4 << 3)) =
            *(const uint4*)(HBin + (gbase + row) * 32 + (g4 << 3));
    }
    if (t < 128) {
        sPx[t] = Pin[(gbase + t) * 2];
        sPy[t] = Pin[(gbase + t) * 2 + 1];
    }
    __syncthreads();

    const int lane = t & 63, w = t >> 6;       // w = 0..3
    const int c = lane & 15, rg = lane >> 4, kk = rg << 3;

    // ---- resident weight fragments ----
    const float* __restrict__ Wm2L = W_msg2 + l * 1024;
    const float* __restrict__ Wp1L = W_pos1 + l * 1024;
    bf16x8 WB1c0, WB1c1, WBpc0, WBpc1, WBac;
#pragma unroll
    for (int j = 0; j < 8; ++j) {
        WB1c0[j] = f2bfs(Wm2L[(kk + j) * 32 + c]);
        WB1c1[j] = f2bfs(Wm2L[(kk + j) * 32 + c + 16]);
        const int pk = ((kk + j) & 1) * 16 + ((kk + j) >> 1);
        WBpc0[j] = f2bfs(Wp1L[pk * 32 + c]);
        WBpc1[j] = f2bfs(Wp1L[pk * 32 + c + 16]);
        WBac[j]  = f2bfs(W_att[l * 32 + pk]);
    }
    float vwr[8];
    {
        const float* wrR = W_msg1 + l * 97 * 32 + 64 * 32 + kk;
#pragma unroll
        for (int j = 0; j < 8; ++j) vwr[j] = wrR[j];
    }
    const float batt  = b_att[l];
    const float vbm20 = b_msg2[l * 32 + c], vbm21 = b_msg2[l * 32 + c + 16];
    const float vbp10 = b_pos1[l * 32 + c], vbp11 = b_pos1[l * 32 + c + 16];
    const float vwp20 = W_pos2[l * 32 + c], vwp21 = W_pos2[l * 32 + c + 16];
    const float bp2   = b_pos2[l];

    unsigned int* mbA = mbuf + w * 320;
    unsigned int* mbB = mbuf + (w + 4) * 320;

    const int dlA = w, dlB = w + 4;
    const int dlocA = (qp << 3) + dlA, dlocB = (qp << 3) + dlB;
    float vhaA[8], vhaB[8];
    {
        const float* haRA = HAin + (gbase + dlocA) * 32 + kk;
        const float* haRB = HAin + (gbase + dlocB) * 32 + kk;
#pragma unroll
        for (int j = 0; j < 8; ++j) { vhaA[j] = haRA[j]; vhaB[j] = haRB[j]; }
    }
    const float pxdA = sPx[dlocA], pydA = sPy[dlocA];
    const float pxdB = sPx[dlocB], pydB = sPy[dlocB];

    float aghc0A = 0.f, aghc1A = 0.f, apxA = 0.f, apyA = 0.f, spnxA = 0.f, spnyA = 0.f;
    float aghc0B = 0.f, aghc1B = 0.f, apxB = 0.f, apyB = 0.f, spnxB = 0.f, spnyB = 0.f;

#pragma unroll 1
    for (int half = 0; half < 2; ++half) {
        const int src = (half << 6) + lane;
        const float sx = sPx[src], sy = sPy[src];
        const float dxA = pxdA - sx, dyA = pydA - sy;
        const float dxB = pxdB - sx, dyB = pydB - sy;
        const float radialA = dxA * dxA + dyA * dyA;
        const float radialB = dxB * dxB + dyB * dyB;
        const float invA = __builtin_amdgcn_rcpf(__builtin_amdgcn_sqrtf(radialA) + 1e-6f);
        const float invB = __builtin_amdgcn_rcpf(__builtin_amdgcn_sqrtf(radialB) + 1e-6f);
        const float pnxA = dxA * invA, pnyA = dyA * invA;
        const float pnxB = dxB * invB, pnyB = dyB * invB;
        spnxA += pnxA; spnyA += pnyA;
        spnxB += pnxB; spnyB += pnyB;
        spn[w * 64 + lane]       = (float2){pnxA, pnyA};
        spn[(w + 4) * 64 + lane] = (float2){pnxB, pnyB};

#pragma unroll
        for (int tt = 0; tt < 4; ++tt) {
            // phase 1: shared src-h read, two independent m1 chains + GEMM-1
            const float rad_tA = __shfl(radialA, c + (tt << 4));
            const float rad_tB = __shfl(radialB, c + (tt << 4));
            uint4 hraw = *(const uint4*)(sHBh + ((half << 6) + c + (tt << 4)) * 40 + kk);
            const unsigned short* hs = (const unsigned short*)&hraw;
            float xA[8], xB[8];
#pragma unroll
            for (int j = 0; j < 8; ++j) {
                const float hb = bf2f(hs[j]);
                xA[j] = fsilu(vhaA[j] + hb + rad_tA * vwr[j]);
                xB[j] = fsilu(vhaB[j] + hb + rad_tB * vwr[j]);
            }
            union { unsigned int u[4]; bf16x8 v; } afA, afB;
#pragma unroll
            for (int d = 0; d < 4; ++d) {
                afA.u[d] = pk_trunc(xA[2 * d], xA[2 * d + 1]);
                afB.u[d] = pk_trunc(xB[2 * d], xB[2 * d + 1]);
            }
            f32x4 a0A = (f32x4){vbm20, vbm20, vbm20, vbm20};
            f32x4 a1A = (f32x4){vbm21, vbm21, vbm21, vbm21};
            f32x4 a0B = a0A, a1B = a1A;
            __builtin_amdgcn_s_setprio(1);     // T5: favor this wave through MFMA cluster
            a0A = __builtin_amdgcn_mfma_f32_16x16x32_bf16(afA.v, WB1c0, a0A, 0, 0, 0);
            a1A = __builtin_amdgcn_mfma_f32_16x16x32_bf16(afA.v, WB1c1, a1A, 0, 0, 0);
            a0B = __builtin_amdgcn_mfma_f32_16x16x32_bf16(afB.v, WB1c0, a0B, 0, 0, 0);
            a1B = __builtin_amdgcn_mfma_f32_16x16x32_bf16(afB.v, WB1c1, a1B, 0, 0, 0);
            __builtin_amdgcn_s_setprio(0);

            // phase 2: silu + pi-stage ungated s (both dsts)
            float s0A[4], s1A[4], s0B[4], s1B[4];
#pragma unroll
            for (int j = 0; j < 4; ++j) {
                s0A[j] = fsilu(a0A[j]);
                s1A[j] = fsilu(a1A[j]);
                s0B[j] = fsilu(a0B[j]);
                s1B[j] = fsilu(a1B[j]);
                mbA[((rg << 2) + j) * 20 + c] = pk_trunc(s0A[j], s1A[j]);
                mbB[((rg << 2) + j) * 20 + c] = pk_trunc(s0B[j], s1B[j]);
            }

            // phase 3: attz/z MFMAs, gate, pw, aggregate (both dsts)
            union { uint4 u; bf16x8 v; } qaA, qaB;
            qaA.u = *(const uint4*)(mbA + c * 20 + (rg << 2));
            qaB.u = *(const uint4*)(mbB + c * 20 + (rg << 2));
            f32x4 zaA = (f32x4){batt, batt, batt, batt};
            f32x4 zaB = zaA;
            f32x4 z0A = (f32x4){0.f, 0.f, 0.f, 0.f};
            f32x4 z1A = z0A, z0B = z0A, z1B = z0A;
            __builtin_amdgcn_s_setprio(1);     // T5: MFMA cluster
            zaA = __builtin_amdgcn_mfma_f32_16x16x32_bf16(qaA.v, WBac,  zaA, 0, 0, 0);
            z0A = __builtin_amdgcn_mfma_f32_16x16x32_bf16(qaA.v, WBpc0, z0A, 0, 0, 0);
            z1A = __builtin_amdgcn_mfma_f32_16x16x32_bf16(qaA.v, WBpc1, z1A, 0, 0, 0);
            zaB = __builtin_amdgcn_mfma_f32_16x16x32_bf16(qaB.v, WBac,  zaB, 0, 0, 0);
            z0B = __builtin_amdgcn_mfma_f32_16x16x32_bf16(qaB.v, WBpc0, z0B, 0, 0, 0);
            z1B = __builtin_amdgcn_mfma_f32_16x16x32_bf16(qaB.v, WBpc1, z1B, 0, 0, 0);
            __builtin_amdgcn_s_setprio(0);
#pragma unroll
            for (int j = 0; j < 4; ++j) {
                const float attA = fsigmoid(zaA[j]);
                const float attB = fsigmoid(zaB[j]);
                aghc0A += attA * s0A[j];
                aghc1A += attA * s1A[j];
                aghc0B += attB * s0B[j];
                aghc1B += attB * s1B[j];
                const float q0A = fsilu(attA * z0A[j] + vbp10);
                const float q1A = fsilu(attA * z1A[j] + vbp11);
                const float q0B = fsilu(attB * z0B[j] + vbp10);
                const float q1B = fsilu(attB * z1B[j] + vbp11);
                const float pwpA = q0A * vwp20 + q1A * vwp21;
                const float pwpB = q0B * vwp20 + q1B * vwp21;
                const float2 pnA = spn[w * 64 + (tt << 4) + (rg << 2) + j];
                const float2 pnB = spn[(w + 4) * 64 + (tt << 4) + (rg << 2) + j];
                apxA += pwpA * pnA.x;
                apyA += pwpA * pnA.y;
                apxB += pwpB * pnB.x;
                apyB += pwpB * pnB.y;
            }
        }
    }

    // epilogue: reduce both dsts, stash aggh/aggp (or write out at l=L-1)
    aghc0A += __shfl_xor(aghc0A, 16); aghc0A += __shfl_xor(aghc0A, 32);
    aghc1A += __shfl_xor(aghc1A, 16); aghc1A += __shfl_xor(aghc1A, 32);
    aghc0B += __shfl_xor(aghc0B, 16); aghc0B += __shfl_xor(aghc0B, 32);
    aghc1B += __shfl_xor(aghc1B, 16); aghc1B += __shfl_xor(aghc1B, 32);
#pragma unroll
    for (int off = 1; off < 64; off <<= 1) {
        apxA  += __shfl_xor(apxA, off);
        apyA  += __shfl_xor(apyA, off);
        spnxA += __shfl_xor(spnxA, off);
        spnyA += __shfl_xor(spnyA, off);
        apxB  += __shfl_xor(apxB, off);
        apyB  += __shfl_xor(apyB, off);
        spnxB += __shfl_xor(spnxB, off);
        spnyB += __shfl_xor(spnyB, off);
    }
    if (l < L - 1) {
        if (lane < 32) {
            sAgg[dlA][lane] = (lane < 16) ? aghc0A : aghc1A;
            sAgg[dlB][lane] = (lane < 16) ? aghc0B : aghc1B;
        }
        if (lane == 0) {
            sAgp[dlA] = (float2){(apxA + bp2 * spnxA) * (1.0f / 128.0f),
                                 (apyA + bp2 * spnyA) * (1.0f / 128.0f)};
            sAgp[dlB] = (float2){(apxB + bp2 * spnxB) * (1.0f / 128.0f),
                                 (apyB + bp2 * spnyB) * (1.0f / 128.0f)};
        }
    } else if (lane == 0) {
        if (dlocA >= NG) {
            out[(g * NSH + (dlocA - NG)) * 2]     = pxdA + (apxA + bp2 * spnxA) * (1.0f / 128.0f);
            out[(g * NSH + (dlocA - NG)) * 2 + 1] = pydA + (apyA + bp2 * spnyA) * (1.0f / 128.0f);
        }
        if (dlocB >= NG) {
            out[(g * NSH + (dlocB - NG)) * 2]     = pxdB + (apxB + bp2 * spnxB) * (1.0f / 128.0f);
            out[(g * NSH + (dlocB - NG)) * 2 + 1] = pydB + (apyB + bp2 * spnyB) * (1.0f / 128.0f);
        }
    }
    if (l == L - 1) return;

    __syncthreads();   // sAgg/sAgp complete; uraw free for node aliases

    // ---------- NODE + pre(l+1) epilogue: single wave, 8 nodes ----------
    // MFMA rows 8..15 computed from stale LDS (garbage), never stored.
    if (t < 64) {
        const int nbase = bx << 3;             // g*128 + qp*8
        float* __restrict__ HAout = ws + (op ? OFF_HA1 : OFF_HA0);
        unsigned short* __restrict__ HBout = (unsigned short*)(ws + (op ? OFF_HB1 : OFF_HB0));
        float* __restrict__ Pout = ws + (op ? OFF_P1 : OFF_P0);

        // stage h (8 rows x 32 f32) — only this block's nodes
        {
            const int row8 = lane >> 3, seg = lane & 7;
            const float* hsrc = ws + OFF_H + (nbase + row8) * 32 + (seg << 2);
#pragma unroll
            for (int j = 0; j < 4; ++j) sH[row8][(seg << 2) + j] = hsrc[j];
        }

        const float* __restrict__ Wn1 = W_node1 + l * 2048;
        const float* __restrict__ Wn2 = W_node2 + l * 1024;
        const float* __restrict__ W1  = W_msg1 + (l + 1) * 97 * 32;
        bf16x8 B1[2][2], B2[2], Ba[2], Bb[2];
#pragma unroll
        for (int j = 0; j < 8; ++j) {
            const int pk = ((kk + j) & 1) * 16 + ((kk + j) >> 1);
#pragma unroll
            for (int nh = 0; nh < 2; ++nh) {
                B1[0][nh][j] = f2bfs(Wn1[(kk + j) * 32 + nh * 16 + c]);
                B1[1][nh][j] = f2bfs(Wn1[(32 + kk + j) * 32 + nh * 16 + c]);
                B2[nh][j]    = f2bfs(Wn2[pk * 32 + nh * 16 + c]);
                Ba[nh][j]    = f2bfs(W1[pk * 32 + nh * 16 + c]);
                Bb[nh][j]    = f2bfs(W1[(32 + pk) * 32 + nh * 16 + c]);
            }
        }

        // temb chain (redundant per block; one writer block per graph)
        const int c2 = lane & 31;
        const float* __restrict__ tin = ws + (par ? OFF_TEMB1 : OFF_TEMB0) + g * 32;
        const float* __restrict__ Wt = W_t + l * 1024;
        float a2 = b_t[l * 32 + c2];
#pragma unroll
        for (int k = 0; k < 32; ++k) a2 += tin[k] * Wt[k * 32 + c2];
        const float tnew = fsilu(a2);
        float tv = b_msg1[(l + 1) * 32 + c2];
#pragma unroll
        for (int k = 0; k < 32; ++k) tv += __shfl(tnew, k) * W1[(65 + k) * 32 + c2];
        if ((bx & 15) == 0 && lane < 32)
            ws[(par ? OFF_TEMB0 : OFF_TEMB1) + g * 32 + lane] = tnew;

        // GEMM1: [h | aggh] @ Wn1   (A rows 8..15 garbage, unstored)
        union { unsigned int u[4]; bf16x8 v; } A0, A1;
#pragma unroll
        for (int d = 0; d < 4; ++d) {
            A0.u[d] = pk_trunc(sH[c][kk + 2 * d],   sH[c][kk + 2 * d + 1]);
            A1.u[d] = pk_trunc(sAgg[c][kk + 2 * d], sAgg[c][kk + 2 * d + 1]);
        }
        f32x4 u1[2];
#pragma unroll
        for (int nh = 0; nh < 2; ++nh) {
            const float bb = b_node1[l * 32 + nh * 16 + c];
            f32x4 acc = (f32x4){bb, bb, bb, bb};
            acc = __builtin_amdgcn_mfma_f32_16x16x32_bf16(A0.v, B1[0][nh], acc, 0, 0, 0);
            acc = __builtin_amdgcn_mfma_f32_16x16x32_bf16(A1.v, B1[1][nh], acc, 0, 0, 0);
            u1[nh] = acc;
        }

        // GEMM2
#pragma unroll
        for (int j = 0; j < 4; ++j)
            nmb[((rg << 2) + j) * 20 + c] = pk_trunc(fsilu(u1[0][j]), fsilu(u1[1][j]));
        union { uint4 q; bf16x8 v; } qa;
        qa.q = *(const uint4*)(nmb + c * 20 + (rg << 2));
        f32x4 u2[2];
#pragma unroll
        for (int nh = 0; nh < 2; ++nh) {
            const float bb = b_node2[l * 32 + nh * 16 + c];
            f32x4 acc = (f32x4){bb, bb, bb, bb};
            u2[nh] = __builtin_amdgcn_mfma_f32_16x16x32_bf16(qa.v, B2[nh], acc, 0, 0, 0);
        }

        // h' = leaky + residual; store (rows 0..7 only) + pi-stage
        float hp0[4], hp1[4];
#pragma unroll
        for (int j = 0; j < 4; ++j) {
            const int row = (rg << 2) + j;
            const float h0 = sH[row][c], h1 = sH[row][c + 16];
            const float v0 = u2[0][j], v1 = u2[1][j];
            hp0[j] = (v0 > 0.f ? v0 : 0.01f * v0) + h0;
            hp1[j] = (v1 > 0.f ? v1 : 0.01f * v1) + h1;
            if (row < 8) {
                ws[OFF_H + (nbase + row) * 32 + c]      = hp0[j];
                ws[OFF_H + (nbase + row) * 32 + c + 16] = hp1[j];
            }
            nmb[row * 20 + c] = pk_trunc(hp0[j], hp1[j]);
        }

        // fused pre(l+1): HA/HB via MFMA -> opposite-parity buffers (rows 0..7)
        qa.q = *(const uint4*)(nmb + c * 20 + (rg << 2));
        f32x4 ha[2], hb[2];
        {
            f32x4 zz = (f32x4){0.f, 0.f, 0.f, 0.f};
#pragma unroll
            for (int nh = 0; nh < 2; ++nh) {
                ha[nh] = __builtin_amdgcn_mfma_f32_16x16x32_bf16(qa.v, Ba[nh], zz, 0, 0, 0);
                hb[nh] = __builtin_amdgcn_mfma_f32_16x16x32_bf16(qa.v, Bb[nh], zz, 0, 0, 0);
            }
        }
        const float tv0 = __shfl(tv, c), tv1 = __shfl(tv, c + 16);
#pragma unroll
        for (int j = 0; j < 4; ++j) {
            const int row = (rg << 2) + j;
            if (row < 8) {
                const int node = nbase + row;
                HAout[node * 32 + c]      = ha[0][j] + tv0;
                HAout[node * 32 + c + 16] = ha[1][j] + tv1;
                HBout[node * 32 + c]      = (unsigned short)f2bfs(hb[0][j]);
                HBout[node * 32 + c + 16] = (unsigned short)f2bfs(hb[1][j]);
            }
        }

        // p' = p + aggp -> opposite-parity buffer (8 nodes)
        if (lane < 16) {
            const int dl2 = lane >> 1, d = lane & 1;
            const int node = nbase + dl2;
            const float ag = d ? sAgp[dl2].y : sAgp[dl2].x;
            Pout[node * 2 + d] = (par ? ws[OFF_P1 + node * 2 + d]
                                      : ws[OFF_P0 + node * 2 + d]) + ag;
        }
    }
}

// ---------------- launch ----------------
extern "C" void kernel_launch(void* const* d_in, const int* in_sizes, int n_in,
                              void* d_out, int out_size, void* d_ws, size_t ws_size,
                              hipStream_t stream)
{
    const float* pos      = (const float*)d_in[0];
    const int*   tsteps   = (const int*)d_in[1];
    const float* goal_pos = (const float*)d_in[2];
    const float* W_hin    = (const float*)d_in[3];
    const float* b_hin    = (const float*)d_in[4];
    const float* W_msg1   = (const float*)d_in[5];
    const float* b_msg1   = (const float*)d_in[6];
    const float* W_msg2   = (const float*)d_in[7];
    const float* b_msg2   = (const float*)d_in[8];
    const float* W_att    = (const float*)d_in[9];
    const float* b_att    = (const float*)d_in[10];
    const float* W_pos1   = (const float*)d_in[11];
    const float* b_pos1   = (const float*)d_in[12];
    const float* W_pos2   = (const float*)d_in[13];
    const float* b_pos2   = (const float*)d_in[14];
    const float* W_node1  = (const float*)d_in[15];
    const float* b_node1  = (const float*)d_in[16];
    const float* W_node2  = (const float*)d_in[17];
    const float* b_node2  = (const float*)d_in[18];
    const float* W_t      = (const float*)d_in[19];
    const float* b_t      = (const float*)d_in[20];

    float* ws = (float*)d_ws;

    setup_pre_kernel<<<1024, 256, 0, stream>>>(ws, pos, tsteps, goal_pos,
                                               W_hin, b_hin, W_msg1, b_msg1);

    for (int l = 0; l < L; ++l)
        edge_kernel<<<1024, 256, 0, stream>>>(ws, W_msg1, b_msg1, W_msg2, b_msg2,
                                              W_att, b_att, W_pos1, b_pos1,
                                              W_pos2, b_pos2, W_node1, b_node1,
                                              W_node2, b_node2, W_t, b_t,
                                              (float*)d_out, l);
}